// Round 1
// baseline (1061.662 us; speedup 1.0000x reference)
//
#include <hip/hip_runtime.h>

#define EPSF 1e-5f
#define DECAYF 0.99f
#define KCODES 2048
#define DIM 256

// ---------------------------------------------------------------------------
// prep: embed[k][d] = embed_sum[k][d] / max(usage[k], eps); e2[k] = ||embed_k||^2
// ---------------------------------------------------------------------------
__global__ __launch_bounds__(256) void prep_kernel(
    const float* __restrict__ embed_sum, const float* __restrict__ usage,
    float* __restrict__ embed, float* __restrict__ e2)
{
    int k = blockIdx.x;
    int d = threadIdx.x;
    float inv = 1.0f / fmaxf(usage[k], EPSF);
    float e = embed_sum[k * DIM + d] * inv;
    embed[k * DIM + d] = e;
    float sq = e * e;
    #pragma unroll
    for (int off = 32; off > 0; off >>= 1) sq += __shfl_down(sq, off, 64);
    __shared__ float ws[4];
    if ((threadIdx.x & 63) == 0) ws[threadIdx.x >> 6] = sq;
    __syncthreads();
    if (threadIdx.x == 0) e2[k] = ws[0] + ws[1] + ws[2] + ws[3];
}

// ---------------------------------------------------------------------------
// argmin: for each row x_n, find argmin_k (e2_k - 2 * x_n . embed_k)
// fp32 tiled GEMM, 128x128 block tile, 8x8 per-thread micro-tile,
// XOR-swizzled float4 LDS (conflict-free ds_read_b128).
// ---------------------------------------------------------------------------
__global__ __launch_bounds__(256, 2) void argmin_kernel(
    const float* __restrict__ x, const float* __restrict__ embed,
    const float* __restrict__ e2, int* __restrict__ flat_ind, int N)
{
    __shared__ float4 xs[128 * 8];   // 16 KB: rows x 8 float4-blocks (32 d's)
    __shared__ float4 es[128 * 8];   // 16 KB

    const int tid = threadIdx.x;
    const int tx  = tid & 15;        // col-group (codes)
    const int ty  = tid >> 4;        // row-group (points)
    const int row0 = blockIdx.x * 128;

    // staging: thread -> (row, half); 2 threads cover one row's 32 floats
    const int sr   = tid >> 1;       // 0..127
    const int sh   = tid & 1;        // 0/1 -> float4 blocks 0-3 / 4-7
    const int skey = (sr >> 3) & 7;  // XOR swizzle key

    float best[8];
    int   bidx[8];
    #pragma unroll
    for (int i = 0; i < 8; ++i) { best[i] = 3.4e38f; bidx[i] = 0; }

    int gr = row0 + sr; if (gr >= N) gr = N - 1;

    for (int kt = 0; kt < KCODES; kt += 128) {
        float acc[8][8] = {};
        for (int dt = 0; dt < DIM; dt += 32) {
            __syncthreads();
            {
                const float4* gx = (const float4*)(x + (size_t)gr * DIM + dt + 16 * sh);
                const float4* ge = (const float4*)(embed + (size_t)(kt + sr) * DIM + dt + 16 * sh);
                #pragma unroll
                for (int q = 0; q < 4; ++q) {
                    int c4 = 4 * sh + q;
                    int sl = sr * 8 + (c4 ^ skey);
                    xs[sl] = gx[q];
                    es[sl] = ge[q];
                }
            }
            __syncthreads();
            #pragma unroll
            for (int d4 = 0; d4 < 8; ++d4) {
                float4 a4[8], b4[8];
                #pragma unroll
                for (int i = 0; i < 8; ++i)
                    a4[i] = xs[(8 * ty + i) * 8 + (d4 ^ (ty & 7))];
                #pragma unroll
                for (int j = 0; j < 8; ++j)
                    b4[j] = es[(8 * tx + j) * 8 + (d4 ^ (tx & 7))];
                #pragma unroll
                for (int i = 0; i < 8; ++i)
                    #pragma unroll
                    for (int j = 0; j < 8; ++j) {
                        acc[i][j] = fmaf(a4[i].x, b4[j].x, acc[i][j]);
                        acc[i][j] = fmaf(a4[i].y, b4[j].y, acc[i][j]);
                        acc[i][j] = fmaf(a4[i].z, b4[j].z, acc[i][j]);
                        acc[i][j] = fmaf(a4[i].w, b4[j].w, acc[i][j]);
                    }
            }
        }
        // epilogue: score = e2_k - 2*dot ; running min with first-index tie-break
        #pragma unroll
        for (int j = 0; j < 8; ++j) {
            int k = kt + 8 * tx + j;
            float e2k = e2[k];
            #pragma unroll
            for (int i = 0; i < 8; ++i) {
                float m = fmaf(-2.0f, acc[i][j], e2k);
                if (m < best[i]) { best[i] = m; bidx[i] = k; }
            }
        }
    }

    // cross-thread (tx) reduction per row via LDS (alias onto xs/es)
    __syncthreads();
    float* bs = (float*)xs;   // [128][16]
    int*   bi = (int*)es;     // [128][16]
    #pragma unroll
    for (int i = 0; i < 8; ++i) {
        bs[(8 * ty + i) * 16 + tx] = best[i];
        bi[(8 * ty + i) * 16 + tx] = bidx[i];
    }
    __syncthreads();
    if (tid < 128) {
        float bb = bs[tid * 16];
        int   ib = bi[tid * 16];
        #pragma unroll
        for (int t = 1; t < 16; ++t) {
            float s = bs[tid * 16 + t];
            int  si = bi[tid * 16 + t];
            if (s < bb || (s == bb && si < ib)) { bb = s; ib = si; }
        }
        int grow = row0 + tid;
        if (grow < N) flat_ind[grow] = ib;
    }
}

// ---------------------------------------------------------------------------
// scatter: quantize gather + EMA scatter-add + index output
// ---------------------------------------------------------------------------
__global__ __launch_bounds__(256) void scatter_kernel(
    const float* __restrict__ x, const float* __restrict__ embed,
    const int* __restrict__ flat_ind,
    float* __restrict__ out_q, float* __restrict__ out_ind_f,
    float* __restrict__ sums, float* __restrict__ counts)
{
    int row = blockIdx.x;
    int d   = threadIdx.x;
    int ind = flat_ind[row];
    float v = x[(size_t)row * DIM + d];
    out_q[(size_t)row * DIM + d] = embed[ind * DIM + d];
    atomicAdd(&sums[ind * DIM + d], v);
    if (d == 0) {
        out_ind_f[row] = (float)ind;
        atomicAdd(&counts[ind], 1.0f);
    }
}

// ---------------------------------------------------------------------------
// finalize: EMA update outputs
// ---------------------------------------------------------------------------
__global__ __launch_bounds__(256) void finalize_kernel(
    const float* __restrict__ embed_sum, const float* __restrict__ usage,
    const float* __restrict__ sums, const float* __restrict__ counts,
    float* __restrict__ out_usage, float* __restrict__ out_embed_sum)
{
    int k = blockIdx.x;
    int d = threadIdx.x;
    out_embed_sum[k * DIM + d] =
        embed_sum[k * DIM + d] * DECAYF + sums[k * DIM + d] * (1.0f - DECAYF);
    if (d == 0)
        out_usage[k] = usage[k] * DECAYF + counts[k] * (1.0f - DECAYF);
}

extern "C" void kernel_launch(void* const* d_in, const int* in_sizes, int n_in,
                              void* d_out, int out_size, void* d_ws, size_t ws_size,
                              hipStream_t stream)
{
    const float* hs        = (const float*)d_in[0];
    const float* embed_sum = (const float*)d_in[1];
    const float* usage     = (const float*)d_in[2];
    const int N = in_sizes[0] / DIM;   // 65536

    float* ws_f   = (float*)d_ws;
    float* embed  = ws_f;                        // K*D
    float* e2     = embed + KCODES * DIM;        // K
    float* sums   = e2 + KCODES;                 // K*D
    float* counts = sums + KCODES * DIM;         // K
    int* flat_ind = (int*)(counts + KCODES);     // N

    float* out_q     = (float*)d_out;            // N*D
    float* out_ind   = out_q + (size_t)N * DIM;  // N
    float* out_usage = out_ind + N;              // K
    float* out_es    = out_usage + KCODES;       // K*D

    // zero EMA accumulators (ws is poisoned; must be deterministic per call)
    hipMemsetAsync(sums, 0, (size_t)(KCODES * DIM + KCODES) * sizeof(float), stream);

    prep_kernel<<<KCODES, 256, 0, stream>>>(embed_sum, usage, embed, e2);
    argmin_kernel<<<(N + 127) / 128, 256, 0, stream>>>(hs, embed, e2, flat_ind, N);
    scatter_kernel<<<N, 256, 0, stream>>>(hs, embed, flat_ind, out_q, out_ind, sums, counts);
    finalize_kernel<<<KCODES, 256, 0, stream>>>(embed_sum, usage, sums, counts, out_usage, out_es);
}

// Round 2
// 454.516 us; speedup vs baseline: 2.3358x; 2.3358x over previous
//
#include <hip/hip_runtime.h>

#define EPSF 1e-5f
#define DECAYF 0.99f
#define KCODES 2048
#define DIM 256

typedef _Float16 f16;
typedef f16 f16x8 __attribute__((ext_vector_type(8)));
typedef float f32x4 __attribute__((ext_vector_type(4)));

#define MFMA16(A, B, C) __builtin_amdgcn_mfma_f32_16x16x32_f16(A, B, C, 0, 0, 0)

__device__ __forceinline__ void gload_lds16(const void* g, void* l) {
    __builtin_amdgcn_global_load_lds(
        (const __attribute__((address_space(1))) void*)g,
        (__attribute__((address_space(3))) void*)l, 16, 0, 0);
}

// ---------------------------------------------------------------------------
// prep: embed fp32 = embed_sum / clamp(usage); e2 = ||embed||^2;
//       eh/el = saturated f16 split of embed.
// ---------------------------------------------------------------------------
__global__ __launch_bounds__(256) void prep_embed_kernel(
    const float* __restrict__ embed_sum, const float* __restrict__ usage,
    float* __restrict__ embed, f16* __restrict__ eh, f16* __restrict__ el,
    float* __restrict__ e2)
{
    int k = blockIdx.x;
    int d = threadIdx.x;
    float inv = 1.0f / fmaxf(usage[k], EPSF);
    float e = embed_sum[k * DIM + d] * inv;
    embed[k * DIM + d] = e;
    // saturate before f16 split: codes with |e|>65000 have astronomically large
    // e2 and can never win argmin; saturation prevents inf/nan poisoning.
    float ec = fminf(fmaxf(e, -65000.0f), 65000.0f);
    f16 h = (f16)ec;
    f16 l = (f16)(ec - (float)h);
    eh[k * DIM + d] = h;
    el[k * DIM + d] = l;
    float sq = e * e;
    #pragma unroll
    for (int off = 32; off > 0; off >>= 1) sq += __shfl_down(sq, off, 64);
    __shared__ float ws[4];
    if ((threadIdx.x & 63) == 0) ws[threadIdx.x >> 6] = sq;
    __syncthreads();
    if (threadIdx.x == 0) e2[k] = ws[0] + ws[1] + ws[2] + ws[3];
}

// ---------------------------------------------------------------------------
// argmin: score(n,k) = e2[k] - 2 * x_n . embed_k via f16-split 3-pass MFMA.
// 128x128 tile, 4 waves (64x64 each, 4x4 16x16x32 fragments), BK=32,
// double-buffered global_load_lds staging, granule-major LDS (conflict-free).
// LDS per buffer: Ax fp32 [8 gran][128 row]x16B = 16KB; Eh,El f16 [4][128]x16B = 8KB each.
// ---------------------------------------------------------------------------
__global__ __launch_bounds__(256, 2) void argmin_kernel(
    const float* __restrict__ x,
    const f16* __restrict__ eh, const f16* __restrict__ el,
    const float* __restrict__ e2, int* __restrict__ flat_ind)
{
    __shared__ char lds[2][32 * 1024];

    const int tid  = threadIdx.x;
    const int w    = tid >> 6;
    const int lane = tid & 63;
    const int l15  = lane & 15;
    const int l4   = lane >> 4;
    const int wrb  = (w >> 1) * 64;   // wave row base within tile
    const int wcb  = (w & 1) * 64;    // wave col base within tile
    const int row0 = blockIdx.x * 128;

    f32x4 acc[4][4];
    float best[4][4];
    int   bidx[4][4];
    #pragma unroll
    for (int i = 0; i < 4; ++i)
        #pragma unroll
        for (int r = 0; r < 4; ++r) { best[i][r] = 3.4e38f; bidx[i][r] = 0; }

    auto stage = [&](int s) {
        const int kt = s >> 3;
        const int dt = (s & 7) * 32;
        char* base = lds[s & 1];
        // Ax (fp32): wave w stages granules 2w, 2w+1 (granule = 4 floats)
        #pragma unroll
        for (int q = 0; q < 4; ++q) {
            const int g   = 2 * w + (q >> 1);
            const int row = (q & 1) * 64 + lane;
            const float* src = x + (size_t)(row0 + row) * DIM + dt + g * 4;
            gload_lds16(src, base + g * 2048 + (q & 1) * 1024);
        }
        // Eh/El (f16): wave w stages granule w (granule = 8 f16)
        #pragma unroll
        for (int q = 0; q < 2; ++q) {
            const int row = q * 64 + lane;
            const f16* sh = eh + (size_t)(kt * 128 + row) * DIM + dt + w * 8;
            const f16* sl = el + (size_t)(kt * 128 + row) * DIM + dt + w * 8;
            gload_lds16(sh, base + 16384 + w * 2048 + q * 1024);
            gload_lds16(sl, base + 24576 + w * 2048 + q * 1024);
        }
    };

    auto compute = [&](int s) {
        const char* base = lds[s & 1];
        f16x8 ah[4], al[4], bh[4], bl[4];
        #pragma unroll
        for (int i = 0; i < 4; ++i) {
            const int row = wrb + i * 16 + l15;
            f32x4 v0 = *(const f32x4*)(base + (2 * l4) * 2048 + row * 16);
            f32x4 v1 = *(const f32x4*)(base + (2 * l4 + 1) * 2048 + row * 16);
            #pragma unroll
            for (int t = 0; t < 4; ++t) {
                f16 h0 = (f16)v0[t];
                ah[i][t] = h0;
                al[i][t] = (f16)(v0[t] - (float)h0);
                f16 h1 = (f16)v1[t];
                ah[i][t + 4] = h1;
                al[i][t + 4] = (f16)(v1[t] - (float)h1);
            }
        }
        #pragma unroll
        for (int j = 0; j < 4; ++j) {
            const int row = wcb + j * 16 + l15;
            bh[j] = *(const f16x8*)(base + 16384 + l4 * 2048 + row * 16);
            bl[j] = *(const f16x8*)(base + 24576 + l4 * 2048 + row * 16);
        }
        #pragma unroll
        for (int i = 0; i < 4; ++i)
            #pragma unroll
            for (int j = 0; j < 4; ++j) {
                acc[i][j] = MFMA16(ah[i], bh[j], acc[i][j]);
                acc[i][j] = MFMA16(ah[i], bl[j], acc[i][j]);
                acc[i][j] = MFMA16(al[i], bh[j], acc[i][j]);
            }
    };

    stage(0);
    __syncthreads();

    for (int kt = 0; kt < 16; ++kt) {
        #pragma unroll
        for (int i = 0; i < 4; ++i)
            #pragma unroll
            for (int j = 0; j < 4; ++j)
                acc[i][j] = (f32x4){0.f, 0.f, 0.f, 0.f};
        #pragma unroll
        for (int d8 = 0; d8 < 8; ++d8) {
            const int s = kt * 8 + d8;
            if (s + 1 < 128) stage(s + 1);
            compute(s);
            __syncthreads();
        }
        // epilogue: running argmin over this 128-col tile
        #pragma unroll
        for (int j = 0; j < 4; ++j) {
            const int col = kt * 128 + wcb + j * 16 + l15;
            const float e2v = e2[col];
            #pragma unroll
            for (int i = 0; i < 4; ++i)
                #pragma unroll
                for (int r = 0; r < 4; ++r) {
                    float m = fmaf(-2.0f, acc[i][j][r], e2v);
                    if (m < best[i][r]) { best[i][r] = m; bidx[i][r] = col; }
                }
        }
    }

    // cross-lane reduce (16 col-lanes per row), then cross-wave combine via LDS
    float* rv = (float*)lds[0];            // [128][2]
    int*   ri = (int*)(lds[0] + 1024);     // [128][2]
    #pragma unroll
    for (int i = 0; i < 4; ++i)
        #pragma unroll
        for (int r = 0; r < 4; ++r) {
            float v = best[i][r];
            int  ix = bidx[i][r];
            #pragma unroll
            for (int m = 1; m <= 8; m <<= 1) {
                float ov = __shfl_xor(v, m, 64);
                int  oix = __shfl_xor(ix, m, 64);
                if (ov < v || (ov == v && oix < ix)) { v = ov; ix = oix; }
            }
            if (l15 == 0) {
                const int rl = wrb + i * 16 + l4 * 4 + r;
                rv[rl * 2 + (w & 1)] = v;
                ri[rl * 2 + (w & 1)] = ix;
            }
        }
    __syncthreads();
    if (tid < 128) {
        float v0 = rv[tid * 2], v1 = rv[tid * 2 + 1];
        int   i0 = ri[tid * 2], i1 = ri[tid * 2 + 1];
        flat_ind[row0 + tid] = (v1 < v0 || (v1 == v0 && i1 < i0)) ? i1 : i0;
    }
}

// ---------------------------------------------------------------------------
// scatter: quantize gather + EMA scatter-add + index output
// ---------------------------------------------------------------------------
__global__ __launch_bounds__(256) void scatter_kernel(
    const float* __restrict__ x, const float* __restrict__ embed,
    const int* __restrict__ flat_ind,
    float* __restrict__ out_q, float* __restrict__ out_ind_f,
    float* __restrict__ sums, float* __restrict__ counts)
{
    int row = blockIdx.x;
    int d   = threadIdx.x;
    int ind = flat_ind[row];
    float v = x[(size_t)row * DIM + d];
    out_q[(size_t)row * DIM + d] = embed[ind * DIM + d];
    atomicAdd(&sums[ind * DIM + d], v);
    if (d == 0) {
        out_ind_f[row] = (float)ind;
        atomicAdd(&counts[ind], 1.0f);
    }
}

// ---------------------------------------------------------------------------
// finalize: EMA update outputs
// ---------------------------------------------------------------------------
__global__ __launch_bounds__(256) void finalize_kernel(
    const float* __restrict__ embed_sum, const float* __restrict__ usage,
    const float* __restrict__ sums, const float* __restrict__ counts,
    float* __restrict__ out_usage, float* __restrict__ out_embed_sum)
{
    int k = blockIdx.x;
    int d = threadIdx.x;
    out_embed_sum[k * DIM + d] =
        embed_sum[k * DIM + d] * DECAYF + sums[k * DIM + d] * (1.0f - DECAYF);
    if (d == 0)
        out_usage[k] = usage[k] * DECAYF + counts[k] * (1.0f - DECAYF);
}

extern "C" void kernel_launch(void* const* d_in, const int* in_sizes, int n_in,
                              void* d_out, int out_size, void* d_ws, size_t ws_size,
                              hipStream_t stream)
{
    const float* hs        = (const float*)d_in[0];
    const float* embed_sum = (const float*)d_in[1];
    const float* usage     = (const float*)d_in[2];
    const int N = in_sizes[0] / DIM;   // 65536

    float* ws_f   = (float*)d_ws;
    float* embed  = ws_f;                         // K*D
    float* e2     = embed + KCODES * DIM;         // K
    float* sums   = e2 + KCODES;                  // K*D
    float* counts = sums + KCODES * DIM;          // K
    f16*   eh     = (f16*)(counts + KCODES);      // K*D f16
    f16*   el     = eh + KCODES * DIM;            // K*D f16
    int* flat_ind = (int*)(el + KCODES * DIM);    // N

    float* out_q     = (float*)d_out;             // N*D
    float* out_ind   = out_q + (size_t)N * DIM;   // N
    float* out_usage = out_ind + N;               // K
    float* out_es    = out_usage + KCODES;        // K*D

    hipMemsetAsync(sums, 0, (size_t)(KCODES * DIM + KCODES) * sizeof(float), stream);

    prep_embed_kernel<<<KCODES, 256, 0, stream>>>(embed_sum, usage, embed, eh, el, e2);
    argmin_kernel<<<N / 128, 256, 0, stream>>>(hs, eh, el, e2, flat_ind);
    scatter_kernel<<<N, 256, 0, stream>>>(hs, embed, flat_ind, out_q, out_ind, sums, counts);
    finalize_kernel<<<KCODES, 256, 0, stream>>>(embed_sum, usage, sums, counts, out_usage, out_es);
}